// Round 10
// baseline (219.652 us; speedup 1.0000x reference)
//
#include <hip/hip_runtime.h>

// DeformationTrackerBiFlowModel — autoregressive Dense-feedback recurrence.
// B=65536 rows, strictly serial T=100 steps per row.
//
// R10 restructure driven by cross-round evidence: dur ≈ bytes / 1.75 TB/s in
// R2/R3/R9 regardless of occupancy/ILP -> effective-BW ceiling from scattered
// 16-48B access granules, not dep-chains. This version makes ALL global
// traffic block-cooperative and coalesced via LDS staging:
//   thread t owns row (bk*256+t) entirely (no cross-lane math);
//   5 windows x 20 steps: stage finger window (float4 loads, 240B contiguous
//   per row) -> fin_lds (stride 61 dwords, odd => conflict-free b32 reads);
//   compute 20 steps; stage outs in out_lds; drain as float4 stores (160B
//   segments, every 64B line fully covered -> no partial-line amplification).
// tanh = 1 - 2/(1+e^{2a}) (exact at +/-inf, R2/R3/R9-validated numerics).

constexpr int Bn   = 65536;
constexpr int Tn   = 100;
constexpr int HID  = 12;
constexpr int ROWS = 256;      // rows per block == threads per block
constexpr int W    = 20;       // steps per window
constexpr int NW   = Tn / W;   // 5 windows, no tail
constexpr int FS   = 61;       // fin_lds row stride in dwords (odd -> 32-bank spread)
constexpr int OS   = 42;       // out_lds row stride in dwords

__device__ __forceinline__ float fast_tanh(float a) {
    // tanh(a) = 1 - 2/(1 + e^{2a}); rcp(inf)=0 handles saturation exactly.
    const float t = __builtin_amdgcn_exp2f(a * 2.885390081777927f); // 2*log2(e)
    return __builtin_fmaf(-2.0f, __builtin_amdgcn_rcpf(1.0f + t), 1.0f);
}

__global__ __launch_bounds__(256, 1) void deform_kernel(
    const float* __restrict__ cp,    // (B,T,2)
    const float* __restrict__ fin,   // (B,T,3)
    const float* __restrict__ Wr,    // (5,12)
    const float* __restrict__ br_,   // (12)
    const float* __restrict__ Wo,    // (14,2)
    const float* __restrict__ bo_,   // (2)
    float* __restrict__ out)         // (B,T,2)
{
    __shared__ float fin_lds[ROWS * FS];   // 62,464 B
    __shared__ float out_lds[ROWS * OS];   // 43,008 B  (total 105.5 KB < 160)

    const int t  = threadIdx.x;
    const int r0 = blockIdx.x * ROWS;

    // Wave-uniform weights -> scalar registers.
    float w0[HID], w1[HID], w2[HID], w3[HID], w4[HID];
    float brv[HID], wo0[HID], wo1[HID];
    #pragma unroll
    for (int j = 0; j < HID; ++j) {
        w0[j] = Wr[0 * HID + j];
        w1[j] = Wr[1 * HID + j];
        w2[j] = Wr[2 * HID + j];
        w3[j] = Wr[3 * HID + j];
        w4[j] = Wr[4 * HID + j];
        brv[j] = br_[j];
        wo0[j] = Wo[(2 + j) * 2 + 0];
        wo1[j] = Wo[(2 + j) * 2 + 1];
    }
    const float wo00 = Wo[0], wo01 = Wo[1];
    const float wo10 = Wo[2], wo11 = Wo[3];
    const float bo0 = bo_[0], bo1 = bo_[1];

    const float cx = cp[(size_t)(r0 + t) * (Tn * 2) + 0];
    const float cy = cp[(size_t)(r0 + t) * (Tn * 2) + 1];
    const float oc0 = bo0 + cx * wo00 + cy * wo10;   // loop-invariant cp0 part
    const float oc1 = bo1 + cx * wo01 + cy * wo11;

    float px = cx, py = cy;   // fed-back output

    const float4* __restrict__ fin4 = reinterpret_cast<const float4*>(fin); // row: 75 f4
    float4* __restrict__ out4 = reinterpret_cast<float4*>(out);             // row: 50 f4

    #pragma unroll 1
    for (int w = 0; w < NW; ++w) {
        // ---- stage finger window w: 15 coalesced float4 loads per thread ----
        float4 v[15];
        #pragma unroll
        for (int k = 0; k < 15; ++k) {
            const int q   = t + k * 256;        // [0, 3840)
            const int row = q / 15;
            const int p4  = q % 15;
            v[k] = fin4[(size_t)(r0 + row) * 75 + w * 15 + p4];
        }
        #pragma unroll
        for (int k = 0; k < 15; ++k) {
            const int q   = t + k * 256;
            const int row = q / 15;
            const int p4  = q % 15;
            float* dst = &fin_lds[row * FS + p4 * 4];
            dst[0] = v[k].x; dst[1] = v[k].y; dst[2] = v[k].z; dst[3] = v[k].w;
        }
        __syncthreads();

        // ---- compute 20 serial steps from LDS ----
        {
            const int fb = t * FS;
            float f0 = fin_lds[fb + 0];
            float f1 = fin_lds[fb + 1];
            float f2 = fin_lds[fb + 2];
            #pragma unroll 1
            for (int s = 0; s < W; ++s) {
                // prefetch next step's finger triple (covers LDS latency)
                float nf0 = 0.f, nf1 = 0.f, nf2 = 0.f;
                if (s + 1 < W) {
                    nf0 = fin_lds[fb + 3 * (s + 1) + 0];
                    nf1 = fin_lds[fb + 3 * (s + 1) + 1];
                    nf2 = fin_lds[fb + 3 * (s + 1) + 2];
                }
                float o0p = 0.f, o1p = 0.f;
                #pragma unroll
                for (int j = 0; j < HID; ++j) {
                    const float g = __builtin_fmaf(f2, w4[j],
                                    __builtin_fmaf(f1, w3[j],
                                    __builtin_fmaf(f0, w2[j], brv[j])));
                    const float a = __builtin_fmaf(py, w1[j],
                                    __builtin_fmaf(px, w0[j], g));
                    const float h = fast_tanh(a);
                    o0p = __builtin_fmaf(h, wo0[j], o0p);
                    o1p = __builtin_fmaf(h, wo1[j], o1p);
                }
                const float o0 = oc0 + o0p;
                const float o1 = oc1 + o1p;
                px = o0; py = o1;
                *reinterpret_cast<float2*>(&out_lds[t * OS + 2 * s]) =
                    make_float2(o0, o1);
                f0 = nf0; f1 = nf1; f2 = nf2;
            }
        }
        __syncthreads();

        // ---- drain output window w: 10 coalesced float4 stores per thread ----
        #pragma unroll
        for (int k = 0; k < 10; ++k) {
            const int q   = t + k * 256;        // [0, 2560)
            const int row = q / 10;
            const int p4  = q % 10;
            const float2* s2 =
                reinterpret_cast<const float2*>(&out_lds[row * OS + p4 * 4]);
            const float2 a0 = s2[0];
            const float2 a1 = s2[1];
            out4[(size_t)(r0 + row) * 50 + w * 10 + p4] =
                make_float4(a0.x, a0.y, a1.x, a1.y);
        }
        // No barrier needed here: next stage writes fin_lds (compute done),
        // and compute(w+1)'s out_lds writes are gated by the post-stage barrier.
    }
}

extern "C" void kernel_launch(void* const* d_in, const int* in_sizes, int n_in,
                              void* d_out, int out_size, void* d_ws, size_t ws_size,
                              hipStream_t stream) {
    const float* cp  = (const float*)d_in[0];  // control_point_input
    const float* fin = (const float*)d_in[1];  // finger_input
    const float* Wr  = (const float*)d_in[2];  // W_rnn
    // d_in[3] = U_rnn — mathematically inert (h0 == 0 each step), unused.
    const float* br  = (const float*)d_in[4];  // b_rnn
    const float* Wo  = (const float*)d_in[5];  // W_out
    const float* bo  = (const float*)d_in[6];  // b_out
    float* out = (float*)d_out;

    deform_kernel<<<dim3(Bn / ROWS), dim3(ROWS), 0, stream>>>(cp, fin, Wr, br, Wo, bo, out);
}